// Round 2
// baseline (176.935 us; speedup 1.0000x reference)
//
#include <hip/hip_runtime.h>

// Problem dims (from reference setup_inputs)
#define BB 4
#define CC 64
#define HH 256
#define WW 256
#define NPIX (HH*WW)          // 65536
#define NCLS 4
#define NPAIR 12              // B*(NCLS-1)
#define HALF 512
#define MAXS 1024
#define NOUT (NPAIR*CC*MAXS)  // 786432

// ---------------------------------------------------------------------------
// K1: fused argmax + 3x3 max-dilation.
// Block = 256 threads = one 16x16 output tile; 18x18 argmax halo in LDS.
// OOB halo entries are 0, which is safe: window always contains the center
// pixel whose argmax >= 0, and labels are >= 0.
// ---------------------------------------------------------------------------
__global__ void k_dargmax(const float* __restrict__ preds, unsigned char* __restrict__ pd) {
    __shared__ unsigned char tile[18][18];
    int b = blockIdx.z;
    int ty0 = blockIdx.y * 16, tx0 = blockIdx.x * 16;
    const float* pb = preds + (size_t)b * NCLS * NPIX;
    for (int i = threadIdx.x; i < 18 * 18; i += 256) {
        int hy = i / 18, hx = i - hy * 18;
        int y = ty0 + hy - 1, x = tx0 + hx - 1;
        unsigned char a = 0;
        if (y >= 0 && y < HH && x >= 0 && x < WW) {
            const float* p = pb + y * WW + x;
            float best = p[0];
            int arg = 0;
#pragma unroll
            for (int c = 1; c < NCLS; ++c) {
                float v = p[(size_t)c * NPIX];
                if (v > best) { best = v; arg = c; }  // first-max wins (jnp.argmax)
            }
            a = (unsigned char)arg;
        }
        tile[hy][hx] = a;
    }
    __syncthreads();
    int ly = threadIdx.x >> 4, lx = threadIdx.x & 15;
    int mv = 0;
#pragma unroll
    for (int dy = 0; dy < 3; ++dy)
#pragma unroll
        for (int dx = 0; dx < 3; ++dx) {
            int v = tile[ly + dy][lx + dx];
            if (v > mv) mv = v;
        }
    pd[b * NPIX + (ty0 + ly) * WW + (tx0 + lx)] = (unsigned char)mv;
}

// ---------------------------------------------------------------------------
// K2: per-(image,class) stream compaction. One block of 1024 threads per pair.
// Thread t owns pixels [t*64, t*64+64) (raster order preserved).
// Packed (hard | easy<<16) counts -> wave shuffle scan -> block scan.
// Slot table staged in LDS, then written to global; also writes the 12 labels.
//  hard rank r  -> slot r                 (if r < 1024)
//  easy rank e  -> slot 512 + excess + e  (if < 1024), excess = max(Nhard-512,0)
// ---------------------------------------------------------------------------
__global__ void __launch_bounds__(1024) k_compact(
        const int* __restrict__ labels, const unsigned char* __restrict__ pd,
        int* __restrict__ slots, float* __restrict__ out) {
    int pair = blockIdx.x;
    int b = pair / 3, cls = pair % 3 + 1;
    const int* lab = labels + b * NPIX;
    const unsigned char* p = pd + b * NPIX;
    int t = threadIdx.x;
    int lane = t & 63, w = t >> 6;          // 16 waves

    __shared__ int sl[MAXS];
    __shared__ unsigned waveSums[16];
    sl[t] = -1;

    // --- count my 64 pixels ---
    int start = t * 64;
    int hc = 0, ec = 0;
#pragma unroll 8
    for (int j = 0; j < 64; ++j) {
        int pix = start + j;
        if (lab[pix] == cls) { if (p[pix] == cls) ec++; else hc++; }
    }
    unsigned mine = (unsigned)hc | ((unsigned)ec << 16);

    // --- wave-inclusive shuffle scan (packed, no overflow: counts <= 65536) ---
    unsigned v = mine;
#pragma unroll
    for (int off = 1; off < 64; off <<= 1) {
        unsigned u = (unsigned)__shfl_up((int)v, off, 64);
        if (lane >= off) v += u;
    }
    if (lane == 63) waveSums[w] = v;
    __syncthreads();
    if (t == 0) {
        unsigned acc = 0;
#pragma unroll
        for (int i = 0; i < 16; ++i) { acc += waveSums[i]; waveSums[i] = acc; }  // inclusive
    }
    __syncthreads();
    unsigned waveBase = (w > 0) ? waveSums[w - 1] : 0u;
    unsigned total = waveSums[15];
    unsigned excl = waveBase + v - mine;    // exclusive prefix for this thread

    int hr = (int)(excl & 0xffffu);
    int er = (int)(excl >> 16);
    int excess = (int)(total & 0xffffu) - HALF;
    if (excess < 0) excess = 0;

    // --- assign my pixels to slots (LDS) ---
#pragma unroll 8
    for (int j = 0; j < 64; ++j) {
        int pix = start + j;
        if (lab[pix] == cls) {
            if (p[pix] != cls) {
                if (hr < MAXS) sl[hr] = pix;
                hr++;
            } else {
                int pos = HALF + excess + er;
                if (pos < MAXS) sl[pos] = pix;
                er++;
            }
        }
    }
    __syncthreads();
    slots[pair * MAXS + t] = sl[t];
    if (t == 0) out[NOUT + pair] = (float)cls;   // feat_label
}

// ---------------------------------------------------------------------------
// K3: gather features; 4 consecutive slots per thread, float4 store.
// ---------------------------------------------------------------------------
__global__ void k_gather(const float* __restrict__ feat, const int* __restrict__ slots,
                         float* __restrict__ out) {
    int i = blockIdx.x * blockDim.x + threadIdx.x;
    const int NQ = NOUT / 4;                 // 196608
    if (i >= NQ) return;
    int q = i << 2;
    int pair = q >> 16;                      // CC*MAXS = 65536
    int c = (q >> 10) & (CC - 1);
    int slot = q & (MAXS - 1);
    int b = pair / 3;
    const float* fp = feat + ((size_t)(b * CC + c)) * NPIX;
    const int* sp = slots + pair * MAXS + slot;
    int p0 = sp[0], p1 = sp[1], p2 = sp[2], p3 = sp[3];
    float4 o;
    o.x = (p0 >= 0) ? fp[p0] : 0.0f;
    o.y = (p1 >= 0) ? fp[p1] : 0.0f;
    o.z = (p2 >= 0) ? fp[p2] : 0.0f;
    o.w = (p3 >= 0) ? fp[p3] : 0.0f;
    ((float4*)out)[i] = o;
}

extern "C" void kernel_launch(void* const* d_in, const int* in_sizes, int n_in,
                              void* d_out, int out_size, void* d_ws, size_t ws_size,
                              hipStream_t stream) {
    const float* feat   = (const float*)d_in[0];  // [B,C,H,W] fp32
    const int*   labels = (const int*)d_in[1];    // [B,H,W] int32
    const float* preds  = (const float*)d_in[2];  // [B,NCLS,H,W] fp32
    float* out = (float*)d_out;

    unsigned char* pd = (unsigned char*)d_ws;                // B*NPIX bytes
    int* slots = (int*)(pd + BB * NPIX);                     // NPAIR*MAXS ints (4B aligned)

    dim3 g1(WW / 16, HH / 16, BB);                           // 16x16x4 blocks
    k_dargmax<<<g1, 256, 0, stream>>>(preds, pd);
    k_compact<<<NPAIR, 1024, 0, stream>>>(labels, pd, slots, out);
    k_gather<<<(NOUT / 4 + 255) / 256, 256, 0, stream>>>(feat, slots, out);
}

// Round 3
// 109.473 us; speedup vs baseline: 1.6162x; 1.6162x over previous
//
#include <hip/hip_runtime.h>

// Problem dims (from reference setup_inputs)
#define BB 4
#define CC 64
#define HH 256
#define WW 256
#define NPIX (HH*WW)          // 65536
#define NCLS 4
#define NPAIR 12              // B*(NCLS-1)
#define HALF 512
#define MAXS 1024
#define NOUT (NPAIR*CC*MAXS)  // 786432
#define CHUNK 4096
#define NCHUNK (NPIX/CHUNK)   // 16

// ---------------------------------------------------------------------------
// K1: fused argmax + 3x3 max-dilation, separable (vertical then horizontal).
// Block = 256 threads = one 4-row x 256-col band; lane x = threadIdx.x so all
// preds loads are perfectly coalesced rows. OOB halo rows use argmax=0 (safe:
// window always contains the center pixel, whose class >= 0).
// ---------------------------------------------------------------------------
__global__ void k_dargmax(const float* __restrict__ preds, unsigned char* __restrict__ pd) {
    __shared__ unsigned char am[6][WW];   // argmax of rows y0-1 .. y0+4
    __shared__ unsigned char vm[4][WW];   // vertical 3-max per output row
    int b = blockIdx.y;
    int y0 = blockIdx.x * 4;
    int x = threadIdx.x;
    const float* pb = preds + (size_t)b * NCLS * NPIX;
#pragma unroll
    for (int r = 0; r < 6; ++r) {
        int y = y0 + r - 1;
        unsigned char a = 0;
        if (y >= 0 && y < HH) {
            const float* p = pb + y * WW + x;
            float best = p[0];
            int arg = 0;
#pragma unroll
            for (int c = 1; c < NCLS; ++c) {
                float v = p[(size_t)c * NPIX];
                if (v > best) { best = v; arg = c; }   // first-max wins (jnp.argmax)
            }
            a = (unsigned char)arg;
        }
        am[r][x] = a;
    }
    __syncthreads();
#pragma unroll
    for (int ry = 0; ry < 4; ++ry) {
        int m = am[ry][x];
        int v1 = am[ry + 1][x], v2 = am[ry + 2][x];
        if (v1 > m) m = v1;
        if (v2 > m) m = v2;
        vm[ry][x] = (unsigned char)m;
    }
    __syncthreads();
#pragma unroll
    for (int ry = 0; ry < 4; ++ry) {
        int m = vm[ry][x];
        if (x > 0)      { int v = vm[ry][x - 1]; if (v > m) m = v; }
        if (x < WW - 1) { int v = vm[ry][x + 1]; if (v > m) m = v; }
        pd[b * NPIX + (y0 + ry) * WW + x] = (unsigned char)m;
    }
}

// ---------------------------------------------------------------------------
// K2: per-(image,chunk) hard/easy counts for ALL 3 classes in one coalesced
// pass (labels read once). Packed hard | easy<<16 per class. Also initializes
// the slot table to -1 (first 12288 global threads).
// ---------------------------------------------------------------------------
__global__ void k_count(const int* __restrict__ labels, const unsigned char* __restrict__ pd,
                        unsigned* __restrict__ chunkCounts, int* __restrict__ slots) {
    int chunk = blockIdx.x, b = blockIdx.y, t = threadIdx.x;
    int gid = (b * NCHUNK + chunk) * 256 + t;
    if (gid < NPAIR * MAXS) slots[gid] = -1;

    const int4*   lab4 = (const int4*)(labels + b * NPIX);
    const uchar4* pd4  = (const uchar4*)(pd + b * NPIX);
    unsigned pk[3] = {0u, 0u, 0u};
#pragma unroll
    for (int j = 0; j < 4; ++j) {
        int idx = chunk * (CHUNK / 4) + j * 256 + t;     // coalesced: lane stride 16B
        int4 lv = lab4[idx];
        uchar4 dv = pd4[idx];
        int ls[4] = {lv.x, lv.y, lv.z, lv.w};
        int ds[4] = {dv.x, dv.y, dv.z, dv.w};
#pragma unroll
        for (int e = 0; e < 4; ++e) {
#pragma unroll
            for (int c = 0; c < 3; ++c) {
                if (ls[e] == c + 1) pk[c] += (ds[e] == c + 1) ? (1u << 16) : 1u;
            }
        }
    }
    // wave reduce (packed fields can't overflow: per-chunk count <= 4096)
    int lane = t & 63, w = t >> 6;
#pragma unroll
    for (int c = 0; c < 3; ++c)
#pragma unroll
        for (int off = 32; off > 0; off >>= 1)
            pk[c] += (unsigned)__shfl_down((int)pk[c], off, 64);
    __shared__ unsigned ws[4][3];
    if (lane == 0) { ws[w][0] = pk[0]; ws[w][1] = pk[1]; ws[w][2] = pk[2]; }
    __syncthreads();
    if (t < 3)
        chunkCounts[(b * 3 + t) * NCHUNK + chunk] =
            ws[0][t] + ws[1][t] + ws[2][t] + ws[3][t];
}

// ---------------------------------------------------------------------------
// K3: tiny per-pair scan of chunk counts -> (hardBase, easyBase) per chunk,
// excess = max(totalHard-512, 0); also writes the 12 feat_label outputs.
// ---------------------------------------------------------------------------
__global__ void k_scan(const unsigned* __restrict__ chunkCounts, int2* __restrict__ chunkBases,
                       int* __restrict__ excessArr, float* __restrict__ out) {
    int t = threadIdx.x;
    if (t < NPAIR) {
        int hb = 0, eb = 0;
        for (int ch = 0; ch < NCHUNK; ++ch) {
            unsigned v = chunkCounts[t * NCHUNK + ch];
            chunkBases[t * NCHUNK + ch] = make_int2(hb, eb);
            hb += (int)(v & 0xffffu);
            eb += (int)(v >> 16);
        }
        int ex = hb - HALF;
        excessArr[t] = ex > 0 ? ex : 0;
        out[NOUT + t] = (float)(t % 3 + 1);
    }
}

// ---------------------------------------------------------------------------
// K4: slot assignment. Grid (chunk, pair), 256 threads, 16 contiguous px per
// thread held in registers (int4/uint4 loads). Packed shuffle scan gives each
// thread its exclusive (hardRank, easyRank); chunks that can't touch any slot
// < 1024 exit before loading anything.
//  hard rank r  -> slot r                 (if r < 1024)
//  easy rank e  -> slot 512 + excess + e  (if < 1024)
// ---------------------------------------------------------------------------
__global__ void k_assign(const int* __restrict__ labels, const unsigned char* __restrict__ pd,
                         const int2* __restrict__ chunkBases, const int* __restrict__ excessArr,
                         int* __restrict__ slots) {
    int chunk = blockIdx.x, pair = blockIdx.y, t = threadIdx.x;
    int b = pair / 3, cls = pair % 3 + 1;
    int2 base = chunkBases[pair * NCHUNK + chunk];
    int excess = excessArr[pair];
    if (base.x >= MAXS && HALF + excess + base.y >= MAXS) return;  // nothing lands

    const int4* lab4 = (const int4*)(labels + b * NPIX + chunk * CHUNK + t * 16);
    const uint4* pd16 = (const uint4*)(pd + b * NPIX + chunk * CHUNK + t * 16);
    int4 l0 = lab4[0], l1 = lab4[1], l2 = lab4[2], l3 = lab4[3];
    uint4 dp = pd16[0];
    int ls[16] = {l0.x, l0.y, l0.z, l0.w, l1.x, l1.y, l1.z, l1.w,
                  l2.x, l2.y, l2.z, l2.w, l3.x, l3.y, l3.z, l3.w};
    unsigned char ds[16];
    unsigned dw[4] = {dp.x, dp.y, dp.z, dp.w};
#pragma unroll
    for (int j = 0; j < 16; ++j) ds[j] = (dw[j >> 2] >> ((j & 3) * 8)) & 0xff;

    unsigned mine = 0;
#pragma unroll
    for (int j = 0; j < 16; ++j)
        if (ls[j] == cls) mine += (ds[j] == cls) ? (1u << 16) : 1u;

    // block scan (4 waves)
    int lane = t & 63, w = t >> 6;
    unsigned v = mine;
#pragma unroll
    for (int off = 1; off < 64; off <<= 1) {
        unsigned u = (unsigned)__shfl_up((int)v, off, 64);
        if (lane >= off) v += u;
    }
    __shared__ unsigned ws[4];
    if (lane == 63) ws[w] = v;
    __syncthreads();
    unsigned waveBase = 0;
    for (int i = 0; i < w; ++i) waveBase += ws[i];
    unsigned excl = waveBase + v - mine;

    int hr = base.x + (int)(excl & 0xffffu);
    int er = base.y + (int)(excl >> 16);
    int pixBase = chunk * CHUNK + t * 16;
    int* sl = slots + pair * MAXS;
#pragma unroll
    for (int j = 0; j < 16; ++j) {
        if (ls[j] == cls) {
            if (ds[j] != cls) {
                if (hr < MAXS) sl[hr] = pixBase + j;
                hr++;
            } else {
                int pos = HALF + excess + er;
                if (pos < MAXS) sl[pos] = pixBase + j;
                er++;
            }
        }
    }
}

// ---------------------------------------------------------------------------
// K5: gather features; 4 consecutive slots per thread, float4 store.
// ---------------------------------------------------------------------------
__global__ void k_gather(const float* __restrict__ feat, const int* __restrict__ slots,
                         float* __restrict__ out) {
    int i = blockIdx.x * blockDim.x + threadIdx.x;
    const int NQ = NOUT / 4;                 // 196608
    if (i >= NQ) return;
    int q = i << 2;
    int pair = q >> 16;                      // CC*MAXS = 65536
    int c = (q >> 10) & (CC - 1);
    int slot = q & (MAXS - 1);
    int b = pair / 3;
    const float* fp = feat + ((size_t)(b * CC + c)) * NPIX;
    const int* sp = slots + pair * MAXS + slot;
    int p0 = sp[0], p1 = sp[1], p2 = sp[2], p3 = sp[3];
    float4 o;
    o.x = (p0 >= 0) ? fp[p0] : 0.0f;
    o.y = (p1 >= 0) ? fp[p1] : 0.0f;
    o.z = (p2 >= 0) ? fp[p2] : 0.0f;
    o.w = (p3 >= 0) ? fp[p3] : 0.0f;
    ((float4*)out)[i] = o;
}

extern "C" void kernel_launch(void* const* d_in, const int* in_sizes, int n_in,
                              void* d_out, int out_size, void* d_ws, size_t ws_size,
                              hipStream_t stream) {
    const float* feat   = (const float*)d_in[0];  // [B,C,H,W] fp32
    const int*   labels = (const int*)d_in[1];    // [B,H,W] int32
    const float* preds  = (const float*)d_in[2];  // [B,NCLS,H,W] fp32
    float* out = (float*)d_out;

    // workspace layout (all offsets 16B-aligned)
    unsigned char* pd = (unsigned char*)d_ws;                  // 262144 B
    int* slots = (int*)(pd + BB * NPIX);                       // 12288 ints
    int2* chunkBases = (int2*)(slots + NPAIR * MAXS);          // 192 int2
    unsigned* chunkCounts = (unsigned*)(chunkBases + NPAIR * NCHUNK);  // 192 uint
    int* excessArr = (int*)(chunkCounts + NPAIR * NCHUNK);     // 12 ints

    k_dargmax<<<dim3(HH / 4, BB), 256, 0, stream>>>(preds, pd);
    k_count<<<dim3(NCHUNK, BB), 256, 0, stream>>>(labels, pd, chunkCounts, slots);
    k_scan<<<1, 64, 0, stream>>>(chunkCounts, chunkBases, excessArr, out);
    k_assign<<<dim3(NCHUNK, NPAIR), 256, 0, stream>>>(labels, pd, chunkBases, excessArr, slots);
    k_gather<<<(NOUT / 4 + 255) / 256, 256, 0, stream>>>(feat, slots, out);
}